// Round 16
// baseline (558.657 us; speedup 1.0000x reference)
//
#include <hip/hip_runtime.h>
#include <math.h>

#define EMBED 128
#define NPB 128   // pairs per block

typedef short s16x8 __attribute__((ext_vector_type(8)));
typedef float f32x16 __attribute__((ext_vector_type(16)));
#define MF(a, b, c) __builtin_amdgcn_mfma_f32_32x32x16_bf16((a), (b), (c), 0, 0, 0)

// float -> bf16 bits, RNE
__device__ __forceinline__ unsigned short f2bf(float f) {
    unsigned u = __float_as_uint(f);
    return (unsigned short)((u + 0x7FFF + ((u >> 16) & 1)) >> 16);
}
__device__ __forceinline__ float bf2f(unsigned short h) {
    return __uint_as_float(((unsigned)h) << 16);
}

// ---------------------------------------------------------------------------
// pairs dtype detector (int64 vs int32 layout).
// ---------------------------------------------------------------------------
__global__ void detect_kernel(const unsigned int* __restrict__ pairs,
                              int* __restrict__ flag) {
    unsigned v = 0;
    int lane = threadIdx.x;
#pragma unroll
    for (int i = 0; i < 8; ++i) v |= pairs[2 * (lane * 8 + i) + 1];
    unsigned long long b = __ballot(v != 0);
    if (lane == 0) *flag = (b != 0ULL) ? 1 : 0;
}

// ---------------------------------------------------------------------------
// Setup: split W1 (512x128) and W2 (128x64) into bf16 hi/lo in FRAG-LINEAR
// layout (exact per-lane MFMA B-operand order; validated rounds 8-15).
// ---------------------------------------------------------------------------
__global__ __launch_bounds__(256) void setup_w_kernel(
    const float* __restrict__ W1, const float* __restrict__ W2,
    unsigned short* __restrict__ W1Fh, unsigned short* __restrict__ W1Fl,
    unsigned short* __restrict__ W2Fh, unsigned short* __restrict__ W2Fl)
{
    int gid = blockIdx.x * 256 + threadIdx.x;
    if (gid < 8192) {                       // W1F
        int f = gid;
        int jt = f >> 11, r = f & 2047;
        int gk = r >> 6, lane = r & 63;
        int j = jt * 32 + (lane & 31);
        int kb = gk * 16 + (lane >> 5) * 8;
#pragma unroll
        for (int e = 0; e < 8; ++e) {
            float w = W1[(size_t)(kb + e) * 128 + j];
            unsigned short hb = f2bf(w);
            unsigned short lb = f2bf(w - bf2f(hb));
            W1Fh[(size_t)f * 8 + e] = hb;
            W1Fl[(size_t)f * 8 + e] = lb;
        }
    } else if (gid < 9216) {                // W2F
        int f = gid - 8192;
        int nt = f >> 9, r = f & 511;
        int gk = r >> 6, lane = r & 63;
        int i = nt * 32 + (lane & 31);
        int kb = gk * 16 + (lane >> 5) * 8;
#pragma unroll
        for (int e = 0; e < 8; ++e) {
            float w = W2[(size_t)(kb + e) * 64 + i];
            unsigned short hb = f2bf(w);
            unsigned short lb = f2bf(w - bf2f(hb));
            W2Fh[(size_t)f * 8 + e] = hb;
            W2Fl[(size_t)f * 8 + e] = lb;
        }
    }
}

// ---------------------------------------------------------------------------
// A-fragment from REGISTER-held h slices (no LDS).
// MODE: 0=hs, 1=ht, 2=hs*ht, 3=|hs-ht|.
// ---------------------------------------------------------------------------
template<int MODE>
__device__ __forceinline__ void make_frag_r(
    const float4* ha, const float4* hb, int ks, s16x8& aH, s16x8& aL)
{
    float av[8], bv[8];
    {
        float4 a0 = ha[2 * ks], a1 = ha[2 * ks + 1];
        av[0] = a0.x; av[1] = a0.y; av[2] = a0.z; av[3] = a0.w;
        av[4] = a1.x; av[5] = a1.y; av[6] = a1.z; av[7] = a1.w;
        float4 b0 = hb[2 * ks], b1 = hb[2 * ks + 1];
        bv[0] = b0.x; bv[1] = b0.y; bv[2] = b0.z; bv[3] = b0.w;
        bv[4] = b1.x; bv[5] = b1.y; bv[6] = b1.z; bv[7] = b1.w;
    }
#pragma unroll
    for (int e = 0; e < 8; ++e) {
        float v;
        if (MODE == 0)      v = av[e];
        else if (MODE == 1) v = bv[e];
        else if (MODE == 2) v = av[e] * bv[e];
        else                v = fabsf(av[e] - bv[e]);
        unsigned short hbit = f2bf(v);
        unsigned short lbit = f2bf(v - bf2f(hbit));
        aH[e] = (short)hbit; aL[e] = (short)lbit;
    }
}

// 4 k-steps of one feature mode; wave = 32 pairs x 128 j.
template<int MODE>
__device__ __forceinline__ void l1_phase_r(
    const float4* ha, const float4* hb,
    const unsigned short* __restrict__ W1Fh, const unsigned short* __restrict__ W1Fl,
    int lane, int gkbase,
    f32x16& ac0, f32x16& ac1, f32x16& ac2, f32x16& ac3)
{
#pragma unroll
    for (int ks = 0; ks < 4; ++ks) {
        s16x8 aH, aL;
        make_frag_r<MODE>(ha, hb, ks, aH, aL);
        int gk = gkbase + ks;
        size_t bi0 = ((size_t)(0 * 32 + gk) * 64 + lane) * 8;
        size_t bi1 = ((size_t)(1 * 32 + gk) * 64 + lane) * 8;
        size_t bi2 = ((size_t)(2 * 32 + gk) * 64 + lane) * 8;
        size_t bi3 = ((size_t)(3 * 32 + gk) * 64 + lane) * 8;
        s16x8 bH0 = *(const s16x8*)&W1Fh[bi0];
        s16x8 bL0 = *(const s16x8*)&W1Fl[bi0];
        s16x8 bH1 = *(const s16x8*)&W1Fh[bi1];
        s16x8 bL1 = *(const s16x8*)&W1Fl[bi1];
        s16x8 bH2 = *(const s16x8*)&W1Fh[bi2];
        s16x8 bL2 = *(const s16x8*)&W1Fl[bi2];
        s16x8 bH3 = *(const s16x8*)&W1Fh[bi3];
        s16x8 bL3 = *(const s16x8*)&W1Fl[bi3];
        ac0 = MF(aH, bH0, ac0); ac0 = MF(aH, bL0, ac0); ac0 = MF(aL, bH0, ac0);
        ac1 = MF(aH, bH1, ac1); ac1 = MF(aH, bL1, ac1); ac1 = MF(aL, bH1, ac1);
        ac2 = MF(aH, bH2, ac2); ac2 = MF(aH, bL2, ac2); ac2 = MF(aL, bH2, ac2);
        ac3 = MF(aH, bH3, ac3); ac3 = MF(aH, bL3, ac3); ac3 = MF(aL, bH3, ac3);
    }
}

// ---------------------------------------------------------------------------
// MFMA pair kernel v9 (round-16): R15's barrier-free register L1 + HALF-M
// layer 2 (two M=64 passes through a half-size fb) -> LDS 69632 -> 34816 B
// -> 4 blocks/CU. fb rows indexed WITHIN the half; waves 0,1 stage half 0
// (pairs 0-63), waves 2,3 stage half 1. All 4 waves compute each L2 half.
// ---------------------------------------------------------------------------
__global__ __launch_bounds__(256) void pair_mfma_kernel(
    const float* __restrict__ h,
    const int* __restrict__ pairs,
    const int* __restrict__ flag,
    const unsigned short* __restrict__ W1Fh, const unsigned short* __restrict__ W1Fl,
    const unsigned short* __restrict__ W2Fh, const unsigned short* __restrict__ W2Fl,
    const float* __restrict__ b1, const float* __restrict__ b2,
    const float* __restrict__ W3, const float* __restrict__ b3,
    float* __restrict__ out, int npairs)
{
    __shared__ __align__(16) char buf[34816];
    unsigned short* fbH = (unsigned short*)buf;            // [64][136] ushort
    unsigned short* fbL = (unsigned short*)(buf + 17408);  // [64][136] ushort

    int tid  = threadIdx.x;
    int lane = tid & 63;
    int w    = tid >> 6;
    int pb   = blockIdx.x * NPB;

    int ghalf = lane >> 5;
    int pA = w * 32 + (lane & 31);

    int p = pb + pA; if (p >= npairs) p = npairs - 1;
    int s, t;
    if (*flag == 0) { s = pairs[4 * p]; t = pairs[4 * p + 2]; }
    else            { s = pairs[2 * p]; t = pairs[2 * p + 1]; }
    const float4* hsP = (const float4*)(h + (size_t)s * EMBED);
    const float4* htP = (const float4*)(h + (size_t)t * EMBED);

    float bj0 = b1[  0 + (lane & 31)];
    float bj1 = b1[ 32 + (lane & 31)];
    float bj2 = b1[ 64 + (lane & 31)];
    float bj3 = b1[ 96 + (lane & 31)];
    f32x16 ac0, ac1, ac2, ac3;
#pragma unroll
    for (int rg = 0; rg < 16; ++rg) { ac0[rg] = bj0; ac1[rg] = bj1; ac2[rg] = bj2; ac3[rg] = bj3; }

    float4 ha[8], hb[8];

    // ---- layer 1, phase 0: dims 0..63 (barrier-free, h in registers) ----
#pragma unroll
    for (int ks = 0; ks < 4; ++ks) {
        ha[2 * ks]     = hsP[ks * 4 + ghalf * 2];
        ha[2 * ks + 1] = hsP[ks * 4 + ghalf * 2 + 1];
        hb[2 * ks]     = htP[ks * 4 + ghalf * 2];
        hb[2 * ks + 1] = htP[ks * 4 + ghalf * 2 + 1];
    }
    l1_phase_r<0>(ha, hb, W1Fh, W1Fl, lane,  0, ac0, ac1, ac2, ac3);
    l1_phase_r<1>(ha, hb, W1Fh, W1Fl, lane,  8, ac0, ac1, ac2, ac3);
    l1_phase_r<2>(ha, hb, W1Fh, W1Fl, lane, 16, ac0, ac1, ac2, ac3);
    l1_phase_r<3>(ha, hb, W1Fh, W1Fl, lane, 24, ac0, ac1, ac2, ac3);

    // ---- layer 1, phase 1: dims 64..127 ----
#pragma unroll
    for (int ks = 0; ks < 4; ++ks) {
        ha[2 * ks]     = hsP[16 + ks * 4 + ghalf * 2];
        ha[2 * ks + 1] = hsP[16 + ks * 4 + ghalf * 2 + 1];
        hb[2 * ks]     = htP[16 + ks * 4 + ghalf * 2];
        hb[2 * ks + 1] = htP[16 + ks * 4 + ghalf * 2 + 1];
    }
    l1_phase_r<0>(ha, hb, W1Fh, W1Fl, lane,  4, ac0, ac1, ac2, ac3);
    l1_phase_r<1>(ha, hb, W1Fh, W1Fl, lane, 12, ac0, ac1, ac2, ac3);
    l1_phase_r<2>(ha, hb, W1Fh, W1Fl, lane, 20, ac0, ac1, ac2, ac3);
    l1_phase_r<3>(ha, hb, W1Fh, W1Fl, lane, 28, ac0, ac1, ac2, ac3);

    // x1 write: in-half row rIdx = (w&1)*32 + crow (RNE split, XOR swizzle)
#define X1WR(ACC, jt) do {                                                   \
    int jbase = (jt) * 32 + (lane & 31);                                     \
    int gj = jbase >> 3, jrem = jbase & 7;                                   \
    _Pragma("unroll")                                                        \
    for (int reg = 0; reg < 16; ++reg) {                                     \
        int rIdx = (w & 1) * 32 + (reg & 3) + 8 * (reg >> 2) + 4 * ghalf;    \
        float x = fmaxf(ACC[reg], 0.0f);                                     \
        unsigned short hbit = f2bf(x);                                       \
        unsigned short lbit = f2bf(x - bf2f(hbit));                          \
        int idx = rIdx * 136 + ((gj ^ ((rIdx >> 3) & 7)) * 8) + jrem;        \
        fbH[idx] = hbit; fbL[idx] = lbit;                                    \
    } } while (0)

    // ---- layer 2 tiling: wave = rows (w&1)*32.., cols nt*32.. ----
    int pB = (w & 1) * 32 + (lane & 31);     // row within half
    int oBbase = pB * 136;
    int sb = (pB >> 3) & 7;
    int nt = w >> 1;
    int iCol = nt * 32 + (lane & 31);
    float b2v = b2[iCol];

#define L2HALF(CC) do {                                                      \
    _Pragma("unroll")                                                        \
    for (int ks = 0; ks < 8; ++ks) {                                         \
        int g = ks * 2 + ghalf;                                              \
        int o = oBbase + ((g ^ sb) * 8);                                     \
        s16x8 aH = *(const s16x8*)&fbH[o];                                   \
        s16x8 aL = *(const s16x8*)&fbL[o];                                   \
        size_t bi = ((size_t)(nt * 8 + ks) * 64 + lane) * 8;                 \
        s16x8 bH = *(const s16x8*)&W2Fh[bi];                                 \
        s16x8 bL = *(const s16x8*)&W2Fl[bi];                                 \
        CC = MF(aH, bH, CC); CC = MF(aH, bL, CC); CC = MF(aL, bH, CC);       \
    } } while (0)

    f32x16 c20, c21;
#pragma unroll
    for (int rg = 0; rg < 16; ++rg) { c20[rg] = b2v; c21[rg] = b2v; }

    // ---- half 0: pairs 0..63 staged by waves 0,1 ----
    if ((w >> 1) == 0) { X1WR(ac0, 0); X1WR(ac1, 1); X1WR(ac2, 2); X1WR(ac3, 3); }
    __syncthreads();
    L2HALF(c20);
    __syncthreads();

    // ---- half 1: pairs 64..127 staged by waves 2,3 ----
    if ((w >> 1) == 1) { X1WR(ac0, 0); X1WR(ac1, 1); X1WR(ac2, 2); X1WR(ac3, 3); }
    __syncthreads();
    L2HALF(c21);
    __syncthreads();   // fb reads done -> reuse region as float reduction buf
#undef X1WR
#undef L2HALF

    // ---- layer 3: relu(x2).W3 partials into LDS [128][68], then row-sum ----
    float* red = (float*)buf;
    {
        float w3v = W3[iCol];
#pragma unroll
        for (int reg = 0; reg < 16; ++reg) {
            int crow = (reg & 3) + 8 * (reg >> 2) + 4 * ghalf;
            red[((w & 1) * 32 + crow) * 68 + iCol] = fmaxf(c20[reg], 0.0f) * w3v;
        }
#pragma unroll
        for (int reg = 0; reg < 16; ++reg) {
            int crow = (reg & 3) + 8 * (reg >> 2) + 4 * ghalf;
            red[(64 + (w & 1) * 32 + crow) * 68 + iCol] = fmaxf(c21[reg], 0.0f) * w3v;
        }
    }
    __syncthreads();

    if (tid < NPB) {
        int po = pb + tid;
        if (po < npairs) {
            const float4* r4 = (const float4*)(red + tid * 68);
            float ssum = 0.0f;
#pragma unroll
            for (int q = 0; q < 16; ++q) {
                float4 v = r4[q];
                ssum += v.x + v.y + v.z + v.w;
            }
            out[po] = ssum + b3[0];
        }
    }
}

// ---------------------------------------------------------------------------
// Fallback: direct per-pair fp32 kernel (only if d_ws too small).
// ---------------------------------------------------------------------------
__global__ __launch_bounds__(256) void mlp_kernel(
    const float* __restrict__ h,
    const int* __restrict__ pairs,
    const int* __restrict__ flag,
    const float* __restrict__ W1, const float* __restrict__ b1,
    const float* __restrict__ W2, const float* __restrict__ b2,
    const float* __restrict__ W3, const float* __restrict__ b3,
    float* __restrict__ out, int npairs)
{
    int p = blockIdx.x * 256 + threadIdx.x;
    if (p >= npairs) return;
    int s, t;
    if (*flag == 0) { s = pairs[4 * p]; t = pairs[4 * p + 2]; }
    else            { s = pairs[2 * p]; t = pairs[2 * p + 1]; }
    const float4* hs4 = (const float4*)(h + (size_t)s * EMBED);
    const float4* ht4 = (const float4*)(h + (size_t)t * EMBED);
    float acc[128];
#pragma unroll
    for (int j = 0; j < 128; ++j) acc[j] = b1[j];
#pragma unroll 1
    for (int d4 = 0; d4 < EMBED / 4; ++d4) {
        float4 a = hs4[d4]; float4 b = ht4[d4];
        float av[4] = {a.x, a.y, a.z, a.w};
        float bv[4] = {b.x, b.y, b.z, b.w};
#pragma unroll
        for (int dd = 0; dd < 4; ++dd) {
            int k = d4 * 4 + dd;
            float f0 = av[dd], f1 = bv[dd];
            float f2 = f0 * f1, f3 = fabsf(f0 - f1);
            const float* w0 = W1 + (size_t)k * 128;
            const float* w1r = w0 + 128 * 128;
            const float* w2r = w0 + 256 * 128;
            const float* w3r = w0 + 384 * 128;
#pragma unroll
            for (int j = 0; j < 128; ++j) {
                float v0 = acc[j];
                v0 = fmaf(f0, w0[j], v0); v0 = fmaf(f1, w1r[j], v0);
                v0 = fmaf(f2, w2r[j], v0); v0 = fmaf(f3, w3r[j], v0);
                acc[j] = v0;
            }
        }
    }
#pragma unroll
    for (int j = 0; j < 128; ++j) acc[j] = fmaxf(acc[j], 0.0f);
    float x2[64];
#pragma unroll
    for (int j = 0; j < 64; ++j) x2[j] = b2[j];
#pragma unroll
    for (int k = 0; k < 128; ++k) {
        float xv = acc[k];
#pragma unroll
        for (int j = 0; j < 64; ++j)
            x2[j] = fmaf(xv, W2[(size_t)k * 64 + j], x2[j]);
    }
    float lg = b3[0];
#pragma unroll
    for (int k = 0; k < 64; ++k)
        lg = fmaf(fmaxf(x2[k], 0.0f), W3[k], lg);
    out[p] = lg;
}

extern "C" void kernel_launch(void* const* d_in, const int* in_sizes, int n_in,
                              void* d_out, int out_size, void* d_ws, size_t ws_size,
                              hipStream_t stream) {
    const float* h   = (const float*)d_in[0];
    const int* pairs = (const int*)d_in[1];
    const float* W1  = (const float*)d_in[2];
    const float* b1  = (const float*)d_in[3];
    const float* W2  = (const float*)d_in[4];
    const float* b2  = (const float*)d_in[5];
    const float* W3  = (const float*)d_in[6];
    const float* b3  = (const float*)d_in[7];
    float* out = (float*)d_out;

    int npairs = out_size;

    int* flag = (int*)d_ws;
    unsigned short* base = (unsigned short*)((char*)d_ws + 16);
    unsigned short* W1Fh = base;                 // 65536 ushort
    unsigned short* W1Fl = base + 65536;         // 65536
    unsigned short* W2Fh = base + 131072;        // 8192
    unsigned short* W2Fl = base + 139264;        // 8192
    size_t need = 16 + (size_t)(65536 * 2 + 8192 * 2) * sizeof(unsigned short);

    detect_kernel<<<1, 64, 0, stream>>>((const unsigned int*)pairs, flag);

    if (ws_size >= need) {
        setup_w_kernel<<<36, 256, 0, stream>>>(W1, W2, W1Fh, W1Fl, W2Fh, W2Fl);
        pair_mfma_kernel<<<(npairs + NPB - 1) / NPB, 256, 0, stream>>>(
            h, pairs, flag, W1Fh, W1Fl, W2Fh, W2Fl, b1, b2, W3, b3, out, npairs);
    } else {
        mlp_kernel<<<(npairs + 255) / 256, 256, 0, stream>>>(
            h, pairs, flag, W1, b1, W2, b2, W3, b3, out, npairs);
    }
}

// Round 17
// 345.401 us; speedup vs baseline: 1.6174x; 1.6174x over previous
//
#include <hip/hip_runtime.h>
#include <math.h>

#define EMBED 128
#define NPB 128   // pairs per block

typedef short s16x8 __attribute__((ext_vector_type(8)));
typedef float f32x16 __attribute__((ext_vector_type(16)));
#define MF(a, b, c) __builtin_amdgcn_mfma_f32_32x32x16_bf16((a), (b), (c), 0, 0, 0)

// float -> bf16 bits, RNE
__device__ __forceinline__ unsigned short f2bf(float f) {
    unsigned u = __float_as_uint(f);
    return (unsigned short)((u + 0x7FFF + ((u >> 16) & 1)) >> 16);
}
__device__ __forceinline__ float bf2f(unsigned short h) {
    return __uint_as_float(((unsigned)h) << 16);
}

// ---------------------------------------------------------------------------
// pairs dtype detector (int64 vs int32 layout).
// ---------------------------------------------------------------------------
__global__ void detect_kernel(const unsigned int* __restrict__ pairs,
                              int* __restrict__ flag) {
    unsigned v = 0;
    int lane = threadIdx.x;
#pragma unroll
    for (int i = 0; i < 8; ++i) v |= pairs[2 * (lane * 8 + i) + 1];
    unsigned long long b = __ballot(v != 0);
    if (lane == 0) *flag = (b != 0ULL) ? 1 : 0;
}

// ---------------------------------------------------------------------------
// Setup: split W1 (512x128) and W2 (128x64) into bf16 hi/lo in FRAG-LINEAR
// layout (exact per-lane MFMA B-operand order; validated rounds 8-16).
// ---------------------------------------------------------------------------
__global__ __launch_bounds__(256) void setup_w_kernel(
    const float* __restrict__ W1, const float* __restrict__ W2,
    unsigned short* __restrict__ W1Fh, unsigned short* __restrict__ W1Fl,
    unsigned short* __restrict__ W2Fh, unsigned short* __restrict__ W2Fl)
{
    int gid = blockIdx.x * 256 + threadIdx.x;
    if (gid < 8192) {                       // W1F
        int f = gid;
        int jt = f >> 11, r = f & 2047;
        int gk = r >> 6, lane = r & 63;
        int j = jt * 32 + (lane & 31);
        int kb = gk * 16 + (lane >> 5) * 8;
#pragma unroll
        for (int e = 0; e < 8; ++e) {
            float w = W1[(size_t)(kb + e) * 128 + j];
            unsigned short hb = f2bf(w);
            unsigned short lb = f2bf(w - bf2f(hb));
            W1Fh[(size_t)f * 8 + e] = hb;
            W1Fl[(size_t)f * 8 + e] = lb;
        }
    } else if (gid < 9216) {                // W2F
        int f = gid - 8192;
        int nt = f >> 9, r = f & 511;
        int gk = r >> 6, lane = r & 63;
        int i = nt * 32 + (lane & 31);
        int kb = gk * 16 + (lane >> 5) * 8;
#pragma unroll
        for (int e = 0; e < 8; ++e) {
            float w = W2[(size_t)(kb + e) * 64 + i];
            unsigned short hb = f2bf(w);
            unsigned short lb = f2bf(w - bf2f(hb));
            W2Fh[(size_t)f * 8 + e] = hb;
            W2Fl[(size_t)f * 8 + e] = lb;
        }
    }
}

// ---------------------------------------------------------------------------
// A-fragment from REGISTER-held h slices (no LDS).
// MODE: 0=hs, 1=ht, 2=hs*ht, 3=|hs-ht|.
// ---------------------------------------------------------------------------
template<int MODE>
__device__ __forceinline__ void make_frag_r(
    const float4* ha, const float4* hb, int ks, s16x8& aH, s16x8& aL)
{
    float av[8], bv[8];
    {
        float4 a0 = ha[2 * ks], a1 = ha[2 * ks + 1];
        av[0] = a0.x; av[1] = a0.y; av[2] = a0.z; av[3] = a0.w;
        av[4] = a1.x; av[5] = a1.y; av[6] = a1.z; av[7] = a1.w;
        float4 b0 = hb[2 * ks], b1 = hb[2 * ks + 1];
        bv[0] = b0.x; bv[1] = b0.y; bv[2] = b0.z; bv[3] = b0.w;
        bv[4] = b1.x; bv[5] = b1.y; bv[6] = b1.z; bv[7] = b1.w;
    }
#pragma unroll
    for (int e = 0; e < 8; ++e) {
        float v;
        if (MODE == 0)      v = av[e];
        else if (MODE == 1) v = bv[e];
        else if (MODE == 2) v = av[e] * bv[e];
        else                v = fabsf(av[e] - bv[e]);
        unsigned short hbit = f2bf(v);
        unsigned short lbit = f2bf(v - bf2f(hbit));
        aH[e] = (short)hbit; aL[e] = (short)lbit;
    }
}

// 4 k-steps of one feature mode; wave = 32 pairs x 128 j.
template<int MODE>
__device__ __forceinline__ void l1_phase_r(
    const float4* ha, const float4* hb,
    const unsigned short* __restrict__ W1Fh, const unsigned short* __restrict__ W1Fl,
    int lane, int gkbase,
    f32x16& ac0, f32x16& ac1, f32x16& ac2, f32x16& ac3)
{
#pragma unroll
    for (int ks = 0; ks < 4; ++ks) {
        s16x8 aH, aL;
        make_frag_r<MODE>(ha, hb, ks, aH, aL);
        int gk = gkbase + ks;
        size_t bi0 = ((size_t)(0 * 32 + gk) * 64 + lane) * 8;
        size_t bi1 = ((size_t)(1 * 32 + gk) * 64 + lane) * 8;
        size_t bi2 = ((size_t)(2 * 32 + gk) * 64 + lane) * 8;
        size_t bi3 = ((size_t)(3 * 32 + gk) * 64 + lane) * 8;
        s16x8 bH0 = *(const s16x8*)&W1Fh[bi0];
        s16x8 bL0 = *(const s16x8*)&W1Fl[bi0];
        s16x8 bH1 = *(const s16x8*)&W1Fh[bi1];
        s16x8 bL1 = *(const s16x8*)&W1Fl[bi1];
        s16x8 bH2 = *(const s16x8*)&W1Fh[bi2];
        s16x8 bL2 = *(const s16x8*)&W1Fl[bi2];
        s16x8 bH3 = *(const s16x8*)&W1Fh[bi3];
        s16x8 bL3 = *(const s16x8*)&W1Fl[bi3];
        ac0 = MF(aH, bH0, ac0); ac0 = MF(aH, bL0, ac0); ac0 = MF(aL, bH0, ac0);
        ac1 = MF(aH, bH1, ac1); ac1 = MF(aH, bL1, ac1); ac1 = MF(aL, bH1, ac1);
        ac2 = MF(aH, bH2, ac2); ac2 = MF(aH, bL2, ac2); ac2 = MF(aL, bH2, ac2);
        ac3 = MF(aH, bH3, ac3); ac3 = MF(aH, bL3, ac3); ac3 = MF(aL, bH3, ac3);
    }
}

// ---------------------------------------------------------------------------
// MFMA pair kernel v10 (round-17): barrier-free register L1 (R15) + WAVE-
// LOCAL layer 2: wave w does M=32 (its own pairs) x N=64 x K=128, with an
// intra-wave C->A transpose through a per-wave [32][37] f32 scratch reused
// across the 4 j-chunks (ac_jt dies right after its chunk -> no VGPR spike).
// LDS = max(4*4736, red 34816) = 34816 B -> 4 blocks/CU. 2 barriers total.
// ---------------------------------------------------------------------------
__global__ __launch_bounds__(256) void pair_mfma_kernel(
    const float* __restrict__ h,
    const int* __restrict__ pairs,
    const int* __restrict__ flag,
    const unsigned short* __restrict__ W1Fh, const unsigned short* __restrict__ W1Fl,
    const unsigned short* __restrict__ W2Fh, const unsigned short* __restrict__ W2Fl,
    const float* __restrict__ b1, const float* __restrict__ b2,
    const float* __restrict__ W3, const float* __restrict__ b3,
    float* __restrict__ out, int npairs)
{
    __shared__ __align__(16) char buf[34816];

    int tid  = threadIdx.x;
    int lane = tid & 63;
    int w    = tid >> 6;
    int pb   = blockIdx.x * NPB;

    int ghalf = lane >> 5;
    int pA = w * 32 + (lane & 31);

    int p = pb + pA; if (p >= npairs) p = npairs - 1;
    int s, t;
    if (*flag == 0) { s = pairs[4 * p]; t = pairs[4 * p + 2]; }
    else            { s = pairs[2 * p]; t = pairs[2 * p + 1]; }
    const float4* hsP = (const float4*)(h + (size_t)s * EMBED);
    const float4* htP = (const float4*)(h + (size_t)t * EMBED);

    float bj0 = b1[  0 + (lane & 31)];
    float bj1 = b1[ 32 + (lane & 31)];
    float bj2 = b1[ 64 + (lane & 31)];
    float bj3 = b1[ 96 + (lane & 31)];
    f32x16 ac0, ac1, ac2, ac3;
#pragma unroll
    for (int rg = 0; rg < 16; ++rg) { ac0[rg] = bj0; ac1[rg] = bj1; ac2[rg] = bj2; ac3[rg] = bj3; }

    float4 ha[8], hb[8];

    // ---- layer 1, phase 0: dims 0..63 (barrier-free, h in registers) ----
#pragma unroll
    for (int ks = 0; ks < 4; ++ks) {
        ha[2 * ks]     = hsP[ks * 4 + ghalf * 2];
        ha[2 * ks + 1] = hsP[ks * 4 + ghalf * 2 + 1];
        hb[2 * ks]     = htP[ks * 4 + ghalf * 2];
        hb[2 * ks + 1] = htP[ks * 4 + ghalf * 2 + 1];
    }
    l1_phase_r<0>(ha, hb, W1Fh, W1Fl, lane,  0, ac0, ac1, ac2, ac3);
    l1_phase_r<1>(ha, hb, W1Fh, W1Fl, lane,  8, ac0, ac1, ac2, ac3);
    l1_phase_r<2>(ha, hb, W1Fh, W1Fl, lane, 16, ac0, ac1, ac2, ac3);
    l1_phase_r<3>(ha, hb, W1Fh, W1Fl, lane, 24, ac0, ac1, ac2, ac3);

    // ---- layer 1, phase 1: dims 64..127 ----
#pragma unroll
    for (int ks = 0; ks < 4; ++ks) {
        ha[2 * ks]     = hsP[16 + ks * 4 + ghalf * 2];
        ha[2 * ks + 1] = hsP[16 + ks * 4 + ghalf * 2 + 1];
        hb[2 * ks]     = htP[16 + ks * 4 + ghalf * 2];
        hb[2 * ks + 1] = htP[16 + ks * 4 + ghalf * 2 + 1];
    }
    l1_phase_r<0>(ha, hb, W1Fh, W1Fl, lane,  4, ac0, ac1, ac2, ac3);
    l1_phase_r<1>(ha, hb, W1Fh, W1Fl, lane, 12, ac0, ac1, ac2, ac3);
    l1_phase_r<2>(ha, hb, W1Fh, W1Fl, lane, 20, ac0, ac1, ac2, ac3);
    l1_phase_r<3>(ha, hb, W1Fh, W1Fl, lane, 28, ac0, ac1, ac2, ac3);

    // ---- layer 2: wave-local, M=32 (own pairs) x N=64 x K=128 ----
    // scratch: per-wave [32][37] f32 (stride 37 coprime 32 -> conflict-free)
    float* scr = ((float*)buf) + w * (32 * 37);

    f32x16 c20, c21;   // N-tile 0 (i 0..31) and 1 (i 32..63)
    {
        float b20 = b2[lane & 31];
        float b21 = b2[32 + (lane & 31)];
#pragma unroll
        for (int rg = 0; rg < 16; ++rg) { c20[rg] = b20; c21[rg] = b21; }
    }

    // write relu(ac_jt) to scratch in (pair,j) layout; read back A-frags.
#define SCRWR(ACC) do {                                                      \
    _Pragma("unroll")                                                        \
    for (int reg = 0; reg < 16; ++reg) {                                     \
        int crow = (reg & 3) + 8 * (reg >> 2) + 4 * ghalf;                   \
        scr[crow * 37 + (lane & 31)] = fmaxf(ACC[reg], 0.0f);                \
    } } while (0)

#define L2CHUNK(jt) do {                                                     \
    _Pragma("unroll")                                                        \
    for (int hh = 0; hh < 2; ++hh) {                                         \
        int off = (lane & 31) * 37 + hh * 16 + ghalf * 8;                    \
        float4 x0 = *(const float4*)(scr + off);                             \
        float4 x1v = *(const float4*)(scr + off + 4);                        \
        float xv[8] = {x0.x, x0.y, x0.z, x0.w, x1v.x, x1v.y, x1v.z, x1v.w};  \
        s16x8 aH, aL;                                                        \
        _Pragma("unroll")                                                    \
        for (int e = 0; e < 8; ++e) {                                        \
            unsigned short hbit = f2bf(xv[e]);                               \
            unsigned short lbit = f2bf(xv[e] - bf2f(hbit));                  \
            aH[e] = (short)hbit; aL[e] = (short)lbit;                        \
        }                                                                    \
        size_t bi0 = ((size_t)(0 * 8 + (jt) * 2 + hh) * 64 + lane) * 8;      \
        size_t bi1 = ((size_t)(1 * 8 + (jt) * 2 + hh) * 64 + lane) * 8;      \
        s16x8 bH0 = *(const s16x8*)&W2Fh[bi0];                               \
        s16x8 bL0 = *(const s16x8*)&W2Fl[bi0];                               \
        s16x8 bH1 = *(const s16x8*)&W2Fh[bi1];                               \
        s16x8 bL1 = *(const s16x8*)&W2Fl[bi1];                               \
        c20 = MF(aH, bH0, c20); c20 = MF(aH, bL0, c20); c20 = MF(aL, bH0, c20); \
        c21 = MF(aH, bH1, c21); c21 = MF(aH, bL1, c21); c21 = MF(aL, bH1, c21); \
    } } while (0)

    SCRWR(ac0); L2CHUNK(0);
    SCRWR(ac1); L2CHUNK(1);
    SCRWR(ac2); L2CHUNK(2);
    SCRWR(ac3); L2CHUNK(3);
#undef SCRWR
#undef L2CHUNK

    __syncthreads();   // all waves done with scratch -> safe to alias as red

    // ---- layer 3: relu(x2).W3 partials into red [128][68], then row-sum ----
    float* red = (float*)buf;
    {
        float w3v0 = W3[lane & 31];
        float w3v1 = W3[32 + (lane & 31)];
#pragma unroll
        for (int reg = 0; reg < 16; ++reg) {
            int crow = (reg & 3) + 8 * (reg >> 2) + 4 * ghalf;
            int pr = w * 32 + crow;
            red[pr * 68 + (lane & 31)]      = fmaxf(c20[reg], 0.0f) * w3v0;
            red[pr * 68 + 32 + (lane & 31)] = fmaxf(c21[reg], 0.0f) * w3v1;
        }
    }
    __syncthreads();

    if (tid < NPB) {
        int po = pb + tid;
        if (po < npairs) {
            const float4* r4 = (const float4*)(red + tid * 68);
            float ssum = 0.0f;
#pragma unroll
            for (int q = 0; q < 16; ++q) {
                float4 v = r4[q];
                ssum += v.x + v.y + v.z + v.w;
            }
            out[po] = ssum + b3[0];
        }
    }
}

// ---------------------------------------------------------------------------
// Fallback: direct per-pair fp32 kernel (only if d_ws too small).
// ---------------------------------------------------------------------------
__global__ __launch_bounds__(256) void mlp_kernel(
    const float* __restrict__ h,
    const int* __restrict__ pairs,
    const int* __restrict__ flag,
    const float* __restrict__ W1, const float* __restrict__ b1,
    const float* __restrict__ W2, const float* __restrict__ b2,
    const float* __restrict__ W3, const float* __restrict__ b3,
    float* __restrict__ out, int npairs)
{
    int p = blockIdx.x * 256 + threadIdx.x;
    if (p >= npairs) return;
    int s, t;
    if (*flag == 0) { s = pairs[4 * p]; t = pairs[4 * p + 2]; }
    else            { s = pairs[2 * p]; t = pairs[2 * p + 1]; }
    const float4* hs4 = (const float4*)(h + (size_t)s * EMBED);
    const float4* ht4 = (const float4*)(h + (size_t)t * EMBED);
    float acc[128];
#pragma unroll
    for (int j = 0; j < 128; ++j) acc[j] = b1[j];
#pragma unroll 1
    for (int d4 = 0; d4 < EMBED / 4; ++d4) {
        float4 a = hs4[d4]; float4 b = ht4[d4];
        float av[4] = {a.x, a.y, a.z, a.w};
        float bv[4] = {b.x, b.y, b.z, b.w};
#pragma unroll
        for (int dd = 0; dd < 4; ++dd) {
            int k = d4 * 4 + dd;
            float f0 = av[dd], f1 = bv[dd];
            float f2 = f0 * f1, f3 = fabsf(f0 - f1);
            const float* w0 = W1 + (size_t)k * 128;
            const float* w1r = w0 + 128 * 128;
            const float* w2r = w0 + 256 * 128;
            const float* w3r = w0 + 384 * 128;
#pragma unroll
            for (int j = 0; j < 128; ++j) {
                float v0 = acc[j];
                v0 = fmaf(f0, w0[j], v0); v0 = fmaf(f1, w1r[j], v0);
                v0 = fmaf(f2, w2r[j], v0); v0 = fmaf(f3, w3r[j], v0);
                acc[j] = v0;
            }
        }
    }
#pragma unroll
    for (int j = 0; j < 128; ++j) acc[j] = fmaxf(acc[j], 0.0f);
    float x2[64];
#pragma unroll
    for (int j = 0; j < 64; ++j) x2[j] = b2[j];
#pragma unroll
    for (int k = 0; k < 128; ++k) {
        float xv = acc[k];
#pragma unroll
        for (int j = 0; j < 64; ++j)
            x2[j] = fmaf(xv, W2[(size_t)k * 64 + j], x2[j]);
    }
    float lg = b3[0];
#pragma unroll
    for (int k = 0; k < 64; ++k)
        lg = fmaf(fmaxf(x2[k], 0.0f), W3[k], lg);
    out[p] = lg;
}

extern "C" void kernel_launch(void* const* d_in, const int* in_sizes, int n_in,
                              void* d_out, int out_size, void* d_ws, size_t ws_size,
                              hipStream_t stream) {
    const float* h   = (const float*)d_in[0];
    const int* pairs = (const int*)d_in[1];
    const float* W1  = (const float*)d_in[2];
    const float* b1  = (const float*)d_in[3];
    const float* W2  = (const float*)d_in[4];
    const float* b2  = (const float*)d_in[5];
    const float* W3  = (const float*)d_in[6];
    const float* b3  = (const float*)d_in[7];
    float* out = (float*)d_out;

    int npairs = out_size;

    int* flag = (int*)d_ws;
    unsigned short* base = (unsigned short*)((char*)d_ws + 16);
    unsigned short* W1Fh = base;                 // 65536 ushort
    unsigned short* W1Fl = base + 65536;         // 65536
    unsigned short* W2Fh = base + 131072;        // 8192
    unsigned short* W2Fl = base + 139264;        // 8192
    size_t need = 16 + (size_t)(65536 * 2 + 8192 * 2) * sizeof(unsigned short);

    detect_kernel<<<1, 64, 0, stream>>>((const unsigned int*)pairs, flag);

    if (ws_size >= need) {
        setup_w_kernel<<<36, 256, 0, stream>>>(W1, W2, W1Fh, W1Fl, W2Fh, W2Fl);
        pair_mfma_kernel<<<(npairs + NPB - 1) / NPB, 256, 0, stream>>>(
            h, pairs, flag, W1Fh, W1Fl, W2Fh, W2Fl, b1, b2, W3, b3, out, npairs);
    } else {
        mlp_kernel<<<(npairs + 255) / 256, 256, 0, stream>>>(
            h, pairs, flag, W1, b1, W2, b2, W3, b3, out, npairs);
    }
}

// Round 18
// 252.259 us; speedup vs baseline: 2.2146x; 1.3692x over previous
//
#include <hip/hip_runtime.h>
#include <math.h>

#define EMBED 128
#define NPB 128   // pairs per block

typedef short s16x8 __attribute__((ext_vector_type(8)));
typedef float f32x16 __attribute__((ext_vector_type(16)));
#define MF(a, b, c) __builtin_amdgcn_mfma_f32_32x32x16_bf16((a), (b), (c), 0, 0, 0)

// float -> bf16 bits, RNE
__device__ __forceinline__ unsigned short f2bf(float f) {
    unsigned u = __float_as_uint(f);
    return (unsigned short)((u + 0x7FFF + ((u >> 16) & 1)) >> 16);
}
__device__ __forceinline__ float bf2f(unsigned short h) {
    return __uint_as_float(((unsigned)h) << 16);
}

// ---------------------------------------------------------------------------
// pairs dtype detector (int64 vs int32 layout).
// ---------------------------------------------------------------------------
__global__ void detect_kernel(const unsigned int* __restrict__ pairs,
                              int* __restrict__ flag) {
    unsigned v = 0;
    int lane = threadIdx.x;
#pragma unroll
    for (int i = 0; i < 8; ++i) v |= pairs[2 * (lane * 8 + i) + 1];
    unsigned long long b = __ballot(v != 0);
    if (lane == 0) *flag = (b != 0ULL) ? 1 : 0;
}

// ---------------------------------------------------------------------------
// Setup: split W1 (512x128) and W2 (128x64) into bf16 hi/lo in FRAG-LINEAR
// layout (exact per-lane MFMA B-operand order; validated rounds 8-17).
// ---------------------------------------------------------------------------
__global__ __launch_bounds__(256) void setup_w_kernel(
    const float* __restrict__ W1, const float* __restrict__ W2,
    unsigned short* __restrict__ W1Fh, unsigned short* __restrict__ W1Fl,
    unsigned short* __restrict__ W2Fh, unsigned short* __restrict__ W2Fl)
{
    int gid = blockIdx.x * 256 + threadIdx.x;
    if (gid < 8192) {                       // W1F
        int f = gid;
        int jt = f >> 11, r = f & 2047;
        int gk = r >> 6, lane = r & 63;
        int j = jt * 32 + (lane & 31);
        int kb = gk * 16 + (lane >> 5) * 8;
#pragma unroll
        for (int e = 0; e < 8; ++e) {
            float w = W1[(size_t)(kb + e) * 128 + j];
            unsigned short hb = f2bf(w);
            unsigned short lb = f2bf(w - bf2f(hb));
            W1Fh[(size_t)f * 8 + e] = hb;
            W1Fl[(size_t)f * 8 + e] = lb;
        }
    } else if (gid < 9216) {                // W2F
        int f = gid - 8192;
        int nt = f >> 9, r = f & 511;
        int gk = r >> 6, lane = r & 63;
        int i = nt * 32 + (lane & 31);
        int kb = gk * 16 + (lane >> 5) * 8;
#pragma unroll
        for (int e = 0; e < 8; ++e) {
            float w = W2[(size_t)(kb + e) * 64 + i];
            unsigned short hb = f2bf(w);
            unsigned short lb = f2bf(w - bf2f(hb));
            W2Fh[(size_t)f * 8 + e] = hb;
            W2Fl[(size_t)f * 8 + e] = lb;
        }
    }
}

// ---------------------------------------------------------------------------
// A-fragment from REGISTER-held h slices (no LDS).
// MODE: 0=hs, 1=ht, 2=hs*ht, 3=|hs-ht|.
// ---------------------------------------------------------------------------
template<int MODE>
__device__ __forceinline__ void make_frag_r(
    const float4* ha, const float4* hb, int ks, s16x8& aH, s16x8& aL)
{
    float av[8], bv[8];
    {
        float4 a0 = ha[2 * ks], a1 = ha[2 * ks + 1];
        av[0] = a0.x; av[1] = a0.y; av[2] = a0.z; av[3] = a0.w;
        av[4] = a1.x; av[5] = a1.y; av[6] = a1.z; av[7] = a1.w;
        float4 b0 = hb[2 * ks], b1 = hb[2 * ks + 1];
        bv[0] = b0.x; bv[1] = b0.y; bv[2] = b0.z; bv[3] = b0.w;
        bv[4] = b1.x; bv[5] = b1.y; bv[6] = b1.z; bv[7] = b1.w;
    }
#pragma unroll
    for (int e = 0; e < 8; ++e) {
        float v;
        if (MODE == 0)      v = av[e];
        else if (MODE == 1) v = bv[e];
        else if (MODE == 2) v = av[e] * bv[e];
        else                v = fabsf(av[e] - bv[e]);
        unsigned short hbit = f2bf(v);
        unsigned short lbit = f2bf(v - bf2f(hbit));
        aH[e] = (short)hbit; aL[e] = (short)lbit;
    }
}

// 4 k-steps of one feature mode; wave = 32 pairs x 128 j.
// T5: s_setprio(1) around the 12-MFMA cluster — waves are barrier-free and
// phase-drifted, so the CU scheduler can favor MFMA-ready waves.
template<int MODE>
__device__ __forceinline__ void l1_phase_r(
    const float4* ha, const float4* hb,
    const unsigned short* __restrict__ W1Fh, const unsigned short* __restrict__ W1Fl,
    int lane, int gkbase,
    f32x16& ac0, f32x16& ac1, f32x16& ac2, f32x16& ac3)
{
#pragma unroll
    for (int ks = 0; ks < 4; ++ks) {
        s16x8 aH, aL;
        make_frag_r<MODE>(ha, hb, ks, aH, aL);
        int gk = gkbase + ks;
        size_t bi0 = ((size_t)(0 * 32 + gk) * 64 + lane) * 8;
        size_t bi1 = ((size_t)(1 * 32 + gk) * 64 + lane) * 8;
        size_t bi2 = ((size_t)(2 * 32 + gk) * 64 + lane) * 8;
        size_t bi3 = ((size_t)(3 * 32 + gk) * 64 + lane) * 8;
        s16x8 bH0 = *(const s16x8*)&W1Fh[bi0];
        s16x8 bL0 = *(const s16x8*)&W1Fl[bi0];
        s16x8 bH1 = *(const s16x8*)&W1Fh[bi1];
        s16x8 bL1 = *(const s16x8*)&W1Fl[bi1];
        s16x8 bH2 = *(const s16x8*)&W1Fh[bi2];
        s16x8 bL2 = *(const s16x8*)&W1Fl[bi2];
        s16x8 bH3 = *(const s16x8*)&W1Fh[bi3];
        s16x8 bL3 = *(const s16x8*)&W1Fl[bi3];
        __builtin_amdgcn_s_setprio(1);
        ac0 = MF(aH, bH0, ac0); ac0 = MF(aH, bL0, ac0); ac0 = MF(aL, bH0, ac0);
        ac1 = MF(aH, bH1, ac1); ac1 = MF(aH, bL1, ac1); ac1 = MF(aL, bH1, ac1);
        ac2 = MF(aH, bH2, ac2); ac2 = MF(aH, bL2, ac2); ac2 = MF(aL, bH2, ac2);
        ac3 = MF(aH, bH3, ac3); ac3 = MF(aH, bL3, ac3); ac3 = MF(aL, bH3, ac3);
        __builtin_amdgcn_s_setprio(0);
    }
}

// ---------------------------------------------------------------------------
// MFMA pair kernel v11 (round-18): EXACT R15 structure (best: 267.6 us) +
// T5 setprio around MFMA clusters. No h LDS staging; layer 1 barrier-free;
// LDS = x1 fragment buffer only; 3 barriers total; RNE split.
// ---------------------------------------------------------------------------
__global__ __launch_bounds__(256) void pair_mfma_kernel(
    const float* __restrict__ h,
    const int* __restrict__ pairs,
    const int* __restrict__ flag,
    const unsigned short* __restrict__ W1Fh, const unsigned short* __restrict__ W1Fl,
    const unsigned short* __restrict__ W2Fh, const unsigned short* __restrict__ W2Fl,
    const float* __restrict__ b1, const float* __restrict__ b2,
    const float* __restrict__ W3, const float* __restrict__ b3,
    float* __restrict__ out, int npairs)
{
    __shared__ __align__(16) char buf[69632];
    unsigned short* fbH = (unsigned short*)buf;        // [128][136] ushort
    unsigned short* fbL = (unsigned short*)(buf + 34816);

    int tid  = threadIdx.x;
    int lane = tid & 63;
    int w    = tid >> 6;
    int pb   = blockIdx.x * NPB;

    int ghalf = lane >> 5;
    int pA = w * 32 + (lane & 31);

    int p = pb + pA; if (p >= npairs) p = npairs - 1;
    int s, t;
    if (*flag == 0) { s = pairs[4 * p]; t = pairs[4 * p + 2]; }
    else            { s = pairs[2 * p]; t = pairs[2 * p + 1]; }
    const float4* hsP = (const float4*)(h + (size_t)s * EMBED);
    const float4* htP = (const float4*)(h + (size_t)t * EMBED);

    float bj0 = b1[  0 + (lane & 31)];
    float bj1 = b1[ 32 + (lane & 31)];
    float bj2 = b1[ 64 + (lane & 31)];
    float bj3 = b1[ 96 + (lane & 31)];
    f32x16 ac0, ac1, ac2, ac3;
#pragma unroll
    for (int rg = 0; rg < 16; ++rg) { ac0[rg] = bj0; ac1[rg] = bj1; ac2[rg] = bj2; ac3[rg] = bj3; }

    float4 ha[8], hb[8];   // this lane's 32+32 floats for current phase

    // ---- phase 0: dims 0..63 (lane's slices: ks*16 + ghalf*8) ----
#pragma unroll
    for (int ks = 0; ks < 4; ++ks) {
        ha[2 * ks]     = hsP[ks * 4 + ghalf * 2];
        ha[2 * ks + 1] = hsP[ks * 4 + ghalf * 2 + 1];
        hb[2 * ks]     = htP[ks * 4 + ghalf * 2];
        hb[2 * ks + 1] = htP[ks * 4 + ghalf * 2 + 1];
    }
    l1_phase_r<0>(ha, hb, W1Fh, W1Fl, lane,  0, ac0, ac1, ac2, ac3);
    l1_phase_r<1>(ha, hb, W1Fh, W1Fl, lane,  8, ac0, ac1, ac2, ac3);
    l1_phase_r<2>(ha, hb, W1Fh, W1Fl, lane, 16, ac0, ac1, ac2, ac3);
    l1_phase_r<3>(ha, hb, W1Fh, W1Fl, lane, 24, ac0, ac1, ac2, ac3);

    // ---- phase 1: dims 64..127 ----
#pragma unroll
    for (int ks = 0; ks < 4; ++ks) {
        ha[2 * ks]     = hsP[16 + ks * 4 + ghalf * 2];
        ha[2 * ks + 1] = hsP[16 + ks * 4 + ghalf * 2 + 1];
        hb[2 * ks]     = htP[16 + ks * 4 + ghalf * 2];
        hb[2 * ks + 1] = htP[16 + ks * 4 + ghalf * 2 + 1];
    }
    l1_phase_r<0>(ha, hb, W1Fh, W1Fl, lane,  4, ac0, ac1, ac2, ac3);
    l1_phase_r<1>(ha, hb, W1Fh, W1Fl, lane, 12, ac0, ac1, ac2, ac3);
    l1_phase_r<2>(ha, hb, W1Fh, W1Fl, lane, 20, ac0, ac1, ac2, ac3);
    l1_phase_r<3>(ha, hb, W1Fh, W1Fl, lane, 28, ac0, ac1, ac2, ac3);

    // ---- x1 = relu(acc): RNE bf16 hi/lo into fb (A-layout, granule XOR) ----
#define X1WR(ACC, jt) do {                                                   \
    int jbase = (jt) * 32 + (lane & 31);                                     \
    int gj = jbase >> 3, jrem = jbase & 7;                                   \
    _Pragma("unroll")                                                        \
    for (int reg = 0; reg < 16; ++reg) {                                     \
        int pr = w * 32 + (reg & 3) + 8 * (reg >> 2) + 4 * ghalf;            \
        float x = fmaxf(ACC[reg], 0.0f);                                     \
        unsigned short hbit = f2bf(x);                                       \
        unsigned short lbit = f2bf(x - bf2f(hbit));                          \
        int idx = pr * 136 + ((gj ^ ((pr >> 3) & 7)) * 8) + jrem;            \
        fbH[idx] = hbit; fbL[idx] = lbit;                                    \
    } } while (0)

    X1WR(ac0, 0); X1WR(ac1, 1); X1WR(ac2, 2); X1WR(ac3, 3);
#undef X1WR
    __syncthreads();

    // ---- layer 2 MFMA: M=128, N=64, K=128 (3-pass) ----
    int pB0 = 64 * (w & 1) + (lane & 31), pB1 = pB0 + 32;
    int oB0base = pB0 * 136, oB1base = pB1 * 136;
    int sb0 = (pB0 >> 3) & 7, sb1 = (pB1 >> 3) & 7;
    int nt = w >> 1;
    int iCol = nt * 32 + (lane & 31);

    float b2v = b2[iCol];
    f32x16 c20, c21;
#pragma unroll
    for (int rg = 0; rg < 16; ++rg) { c20[rg] = b2v; c21[rg] = b2v; }

#pragma unroll
    for (int ks = 0; ks < 8; ++ks) {
        int g = ks * 2 + ghalf;
        int o0 = oB0base + (g ^ sb0) * 8;
        int o1 = oB1base + (g ^ sb1) * 8;
        s16x8 aH0 = *(const s16x8*)&fbH[o0];
        s16x8 aL0 = *(const s16x8*)&fbL[o0];
        s16x8 aH1 = *(const s16x8*)&fbH[o1];
        s16x8 aL1 = *(const s16x8*)&fbL[o1];
        size_t bi = ((size_t)(nt * 8 + ks) * 64 + lane) * 8;
        s16x8 bH = *(const s16x8*)&W2Fh[bi];
        s16x8 bL = *(const s16x8*)&W2Fl[bi];
        __builtin_amdgcn_s_setprio(1);
        c20 = MF(aH0, bH, c20); c20 = MF(aH0, bL, c20); c20 = MF(aL0, bH, c20);
        c21 = MF(aH1, bH, c21); c21 = MF(aH1, bL, c21); c21 = MF(aL1, bH, c21);
        __builtin_amdgcn_s_setprio(0);
    }
    __syncthreads();   // fb reads done -> reuse region as float reduction buf

    // ---- layer 3: relu(x2).W3 partials into LDS [128][68], then row-sum ----
    float* red = (float*)buf;
    {
        float w3v = W3[iCol];
#pragma unroll
        for (int reg = 0; reg < 16; ++reg) {
            int pr = 64 * (w & 1) + (reg & 3) + 8 * (reg >> 2) + 4 * ghalf;
            red[pr * 68 + iCol] = fmaxf(c20[reg], 0.0f) * w3v;
        }
#pragma unroll
        for (int reg = 0; reg < 16; ++reg) {
            int pr = 64 * (w & 1) + 32 + (reg & 3) + 8 * (reg >> 2) + 4 * ghalf;
            red[pr * 68 + iCol] = fmaxf(c21[reg], 0.0f) * w3v;
        }
    }
    __syncthreads();

    if (tid < NPB) {
        int po = pb + tid;
        if (po < npairs) {
            const float4* r4 = (const float4*)(red + tid * 68);
            float ssum = 0.0f;
#pragma unroll
            for (int q = 0; q < 16; ++q) {
                float4 v = r4[q];
                ssum += v.x + v.y + v.z + v.w;
            }
            out[po] = ssum + b3[0];
        }
    }
}

// ---------------------------------------------------------------------------
// Fallback: direct per-pair fp32 kernel (only if d_ws too small).
// ---------------------------------------------------------------------------
__global__ __launch_bounds__(256) void mlp_kernel(
    const float* __restrict__ h,
    const int* __restrict__ pairs,
    const int* __restrict__ flag,
    const float* __restrict__ W1, const float* __restrict__ b1,
    const float* __restrict__ W2, const float* __restrict__ b2,
    const float* __restrict__ W3, const float* __restrict__ b3,
    float* __restrict__ out, int npairs)
{
    int p = blockIdx.x * 256 + threadIdx.x;
    if (p >= npairs) return;
    int s, t;
    if (*flag == 0) { s = pairs[4 * p]; t = pairs[4 * p + 2]; }
    else            { s = pairs[2 * p]; t = pairs[2 * p + 1]; }
    const float4* hs4 = (const float4*)(h + (size_t)s * EMBED);
    const float4* ht4 = (const float4*)(h + (size_t)t * EMBED);
    float acc[128];
#pragma unroll
    for (int j = 0; j < 128; ++j) acc[j] = b1[j];
#pragma unroll 1
    for (int d4 = 0; d4 < EMBED / 4; ++d4) {
        float4 a = hs4[d4]; float4 b = ht4[d4];
        float av[4] = {a.x, a.y, a.z, a.w};
        float bv[4] = {b.x, b.y, b.z, b.w};
#pragma unroll
        for (int dd = 0; dd < 4; ++dd) {
            int k = d4 * 4 + dd;
            float f0 = av[dd], f1 = bv[dd];
            float f2 = f0 * f1, f3 = fabsf(f0 - f1);
            const float* w0 = W1 + (size_t)k * 128;
            const float* w1r = w0 + 128 * 128;
            const float* w2r = w0 + 256 * 128;
            const float* w3r = w0 + 384 * 128;
#pragma unroll
            for (int j = 0; j < 128; ++j) {
                float v0 = acc[j];
                v0 = fmaf(f0, w0[j], v0); v0 = fmaf(f1, w1r[j], v0);
                v0 = fmaf(f2, w2r[j], v0); v0 = fmaf(f3, w3r[j], v0);
                acc[j] = v0;
            }
        }
    }
#pragma unroll
    for (int j = 0; j < 128; ++j) acc[j] = fmaxf(acc[j], 0.0f);
    float x2[64];
#pragma unroll
    for (int j = 0; j < 64; ++j) x2[j] = b2[j];
#pragma unroll
    for (int k = 0; k < 128; ++k) {
        float xv = acc[k];
#pragma unroll
        for (int j = 0; j < 64; ++j)
            x2[j] = fmaf(xv, W2[(size_t)k * 64 + j], x2[j]);
    }
    float lg = b3[0];
#pragma unroll
    for (int k = 0; k < 64; ++k)
        lg = fmaf(fmaxf(x2[k], 0.0f), W3[k], lg);
    out[p] = lg;
}

extern "C" void kernel_launch(void* const* d_in, const int* in_sizes, int n_in,
                              void* d_out, int out_size, void* d_ws, size_t ws_size,
                              hipStream_t stream) {
    const float* h   = (const float*)d_in[0];
    const int* pairs = (const int*)d_in[1];
    const float* W1  = (const float*)d_in[2];
    const float* b1  = (const float*)d_in[3];
    const float* W2  = (const float*)d_in[4];
    const float* b2  = (const float*)d_in[5];
    const float* W3  = (const float*)d_in[6];
    const float* b3  = (const float*)d_in[7];
    float* out = (float*)d_out;

    int npairs = out_size;

    int* flag = (int*)d_ws;
    unsigned short* base = (unsigned short*)((char*)d_ws + 16);
    unsigned short* W1Fh = base;                 // 65536 ushort
    unsigned short* W1Fl = base + 65536;         // 65536
    unsigned short* W2Fh = base + 131072;        // 8192
    unsigned short* W2Fl = base + 139264;        // 8192
    size_t need = 16 + (size_t)(65536 * 2 + 8192 * 2) * sizeof(unsigned short);

    detect_kernel<<<1, 64, 0, stream>>>((const unsigned int*)pairs, flag);

    if (ws_size >= need) {
        setup_w_kernel<<<36, 256, 0, stream>>>(W1, W2, W1Fh, W1Fl, W2Fh, W2Fl);
        pair_mfma_kernel<<<(npairs + NPB - 1) / NPB, 256, 0, stream>>>(
            h, pairs, flag, W1Fh, W1Fl, W2Fh, W2Fl, b1, b2, W3, b3, out, npairs);
    } else {
        mlp_kernel<<<(npairs + 255) / 256, 256, 0, stream>>>(
            h, pairs, flag, W1, b1, W2, b2, W3, b3, out, npairs);
    }
}